// Round 2
// baseline (1829.592 us; speedup 1.0000x reference)
//
#include <hip/hip_runtime.h>
#include <cstdio>
#include <cstdint>

typedef _Float16 f16;
typedef f16 hf2   __attribute__((ext_vector_type(2)));
typedef f16 f16x8 __attribute__((ext_vector_type(8)));
typedef float f32x4 __attribute__((ext_vector_type(4)));
typedef unsigned int   u32;
typedef unsigned short u16;

#define B_    256
#define S_    512
#define IN_   32
#define H_    256
#define G3_   768
#define D_    32
#define PRED_ 96
#define TC_   32          // time-chunk
#define XPAD_ 776         // padded xpc row (halves)

#if __has_builtin(__builtin_amdgcn_fdot2)
__device__ __forceinline__ float fdot2(hf2 a, hf2 b, float c) {
  return __builtin_amdgcn_fdot2(a, b, c, false);
}
#else
__device__ __forceinline__ float fdot2(hf2 a, hf2 b, float c) {
  return c + (float)a[0] * (float)b[0] + (float)a[1] * (float)b[1];
}
#endif

__device__ __forceinline__ float sigm(float x) {
  return __builtin_amdgcn_rcpf(1.f + __expf(-x));
}
__device__ __forceinline__ float tanh_fast(float x) {
  return 1.f - 2.f * __builtin_amdgcn_rcpf(__expf(2.f * x) + 1.f);
}
__device__ __forceinline__ hf2 bc2(u32 v) { return __builtin_bit_cast(hf2, v); }

__global__ void f32_to_f16_k(const float* __restrict__ in, f16* __restrict__ out, int n) {
  int i = blockIdx.x * blockDim.x + threadIdx.x;
  if (i < n) out[i] = (f16)in[i];
}

__device__ __forceinline__ f16x8 cvt8(const float* p) {
  float4 lo = ((const float4*)p)[0];
  float4 hi = ((const float4*)p)[1];
  f16x8 r;
  r[0] = (f16)lo.x; r[1] = (f16)lo.y; r[2] = (f16)lo.z; r[3] = (f16)lo.w;
  r[4] = (f16)hi.x; r[5] = (f16)hi.y; r[6] = (f16)hi.z; r[7] = (f16)hi.w;
  return r;
}

#define ACC4(acc, warr)                       \
  acc = fdot2(warr[cc * 4 + 0], hh0, acc);    \
  acc = fdot2(warr[cc * 4 + 1], hh1, acc);    \
  acc = fdot2(warr[cc * 4 + 2], hh2, acc);    \
  acc = fdot2(warr[cc * 4 + 3], hh3, acc);

// One WG (512 thr) per batch row. Register-stationary fp16 W_hh:
// thread (j2=tid>>2, kq=tid&3) owns rows {j2, j2+128} x {r,z,n}, k-slice
// [kq*64, kq*64+64). Per 32-step chunk, an MFMA phase computes
// xpc = A_chunk @ Wih^T + bih into LDS (rows padded to 776 halves).
template <int LAYER>
__global__ __launch_bounds__(512, 2) void gru_fused(
    const void* __restrict__ Asrc,   // L0: x f32 [B*S][32]; L1: h16 f16 [B*S][256]
    const f16* __restrict__ Wih,     // f16 [768][KK]
    const float* __restrict__ bih,   // [768]
    const float* __restrict__ Whh,   // f32 [768][256]
    const float* __restrict__ bhh,   // [768]
    f16* __restrict__ h16_out,       // [B*S][256] (LAYER==0)
    float* __restrict__ hfinal) {    // [B][256]   (LAYER==1)
  constexpr int KK = LAYER ? H_ : IN_;
  const int b   = blockIdx.x;
  const int tid = threadIdx.x;
  const int j2 = tid >> 2, kq = tid & 3;
  const int wv = tid >> 6, lane = tid & 63, lm = lane & 15, q = lane >> 4;

  // ---- W_hh -> registers (fp16), 192 VGPRs ----
  hf2 w[2][3][32];
#pragma unroll
  for (int jj = 0; jj < 2; jj++) {
    const int j = j2 + jj * 128;
#pragma unroll
    for (int g = 0; g < 3; g++) {
      const float4* src = (const float4*)(Whh + (size_t)(g * 256 + j) * 256 + kq * 64);
#pragma unroll
      for (int u = 0; u < 16; u++) {
        float4 f = src[u];
        w[jj][g][2 * u]     = hf2{(f16)f.x, (f16)f.y};
        w[jj][g][2 * u + 1] = hf2{(f16)f.z, (f16)f.w};
      }
    }
  }
  float bh[2][3];
#pragma unroll
  for (int jj = 0; jj < 2; jj++)
#pragma unroll
    for (int g = 0; g < 3; g++) bh[jj][g] = bhh[g * 256 + j2 + jj * 128];

  __shared__ u16 xpc[TC_ * XPAD_];                 // 49,664 B
  __shared__ __align__(16) u16 h2u[288];           // h state fp16, 4 slices of 72
  if (tid < 144) ((u32*)h2u)[tid] = 0u;
  float h[2] = {0.f, 0.f};
  f16* h16p = (LAYER == 0) ? (h16_out + (size_t)b * S_ * H_) : nullptr;

  for (int c = 0; c < S_ / TC_; ++c) {
    const int t0 = c * TC_;
    // ---------- xp GEMM phase: wave wv owns n in [wv*96, wv*96+96) ----------
#pragma unroll 1
    for (int nt = 0; nt < 6; ++nt) {
      const int n0 = wv * 96 + nt * 16;
      const f16* Bp = Wih + (size_t)(n0 + lm) * KK + q * 8;
      f32x4 ac0 = {0.f, 0.f, 0.f, 0.f}, ac1 = ac0;
#pragma unroll
      for (int k0 = 0; k0 < KK; k0 += 32) {
        f16x8 bv = *(const f16x8*)(Bp + k0);
        f16x8 a0, a1;
        if constexpr (LAYER == 0) {
          const float* xr = (const float*)Asrc + ((size_t)b * S_ + t0 + lm) * IN_ + k0 + q * 8;
          a0 = cvt8(xr);
          a1 = cvt8(xr + 16 * IN_);
        } else {
          const f16* ar = (const f16*)Asrc + ((size_t)b * S_ + t0 + lm) * H_ + k0 + q * 8;
          a0 = *(const f16x8*)ar;
          a1 = *(const f16x8*)(ar + 16 * H_);
        }
        ac0 = __builtin_amdgcn_mfma_f32_16x16x32_f16(a0, bv, ac0, 0, 0, 0);
        ac1 = __builtin_amdgcn_mfma_f32_16x16x32_f16(a1, bv, ac1, 0, 0, 0);
      }
      const float bb = bih[n0 + lm];
#pragma unroll
      for (int r = 0; r < 4; ++r) {   // D: col=lane&15 (n), row=q*4+r (m)
        xpc[(q * 4 + r) * XPAD_ + n0 + lm]        = __builtin_bit_cast(u16, (f16)(ac0[r] + bb));
        xpc[(16 + q * 4 + r) * XPAD_ + n0 + lm]   = __builtin_bit_cast(u16, (f16)(ac1[r] + bb));
      }
    }
    __syncthreads();

    // ---------- 32 recurrence steps ----------
    for (int tl = 0; tl < TC_; ++tl) {
      float ar0 = 0.f, az0 = 0.f, an0 = 0.f, ar1 = 0.f, az1 = 0.f, an1 = 0.f;
      const uint4* hb = (const uint4*)h2u + kq * 9;
#pragma unroll
      for (int cc = 0; cc < 8; ++cc) {
        uint4 hv = hb[cc];
        hf2 hh0 = bc2(hv.x), hh1 = bc2(hv.y), hh2 = bc2(hv.z), hh3 = bc2(hv.w);
        ACC4(ar0, w[0][0]); ACC4(az0, w[0][1]); ACC4(an0, w[0][2]);
        ACC4(ar1, w[1][0]); ACC4(az1, w[1][1]); ACC4(an1, w[1][2]);
      }
      ar0 += __shfl_xor(ar0, 1); ar0 += __shfl_xor(ar0, 2);
      az0 += __shfl_xor(az0, 1); az0 += __shfl_xor(az0, 2);
      an0 += __shfl_xor(an0, 1); an0 += __shfl_xor(an0, 2);
      ar1 += __shfl_xor(ar1, 1); ar1 += __shfl_xor(ar1, 2);
      az1 += __shfl_xor(az1, 1); az1 += __shfl_xor(az1, 2);
      an1 += __shfl_xor(an1, 1); an1 += __shfl_xor(an1, 2);

      const u16* xrow = xpc + tl * XPAD_;
      {
        float xr = (float)__builtin_bit_cast(f16, xrow[j2]);
        float xz = (float)__builtin_bit_cast(f16, xrow[256 + j2]);
        float xn = (float)__builtin_bit_cast(f16, xrow[512 + j2]);
        float r = sigm(xr + ar0 + bh[0][0]);
        float z = sigm(xz + az0 + bh[0][1]);
        float n = tanh_fast(xn + r * (an0 + bh[0][2]));
        h[0] = (1.f - z) * n + z * h[0];
      }
      {
        const int j = j2 + 128;
        float xr = (float)__builtin_bit_cast(f16, xrow[j]);
        float xz = (float)__builtin_bit_cast(f16, xrow[256 + j]);
        float xn = (float)__builtin_bit_cast(f16, xrow[512 + j]);
        float r = sigm(xr + ar1 + bh[1][0]);
        float z = sigm(xz + az1 + bh[1][1]);
        float n = tanh_fast(xn + r * (an1 + bh[1][2]));
        h[1] = (1.f - z) * n + z * h[1];
      }
      __syncthreads();   // all reads of h2u / xpc row done
      if (kq == 0) {
        h2u[(j2 >> 6) * 72 + (j2 & 63)] = __builtin_bit_cast(u16, (f16)h[0]);
        if constexpr (LAYER == 0) h16p[(size_t)(t0 + tl) * H_ + j2] = (f16)h[0];
      } else if (kq == 1) {
        const int jb = j2 + 128;
        h2u[(jb >> 6) * 72 + (jb & 63)] = __builtin_bit_cast(u16, (f16)h[1]);
        if constexpr (LAYER == 0) h16p[(size_t)(t0 + tl) * H_ + jb] = (f16)h[1];
      }
      __syncthreads();   // h2u update visible; xpc row free for next chunk
    }
  }
  if constexpr (LAYER == 1) {
    if (kq == 0)      hfinal[b * H_ + j2]       = h[0];
    else if (kq == 1) hfinal[b * H_ + 128 + j2] = h[1];
  }
}

// ---------------- projection + 96-step rollout ------------------------------
__global__ __launch_bounds__(128) void proj_rollout(
    const float* __restrict__ hfinal, const float* __restrict__ Wp,
    const float* __restrict__ bp, const float* __restrict__ Cm,
    const float* __restrict__ rld, const float* __restrict__ rtd,
    const float* __restrict__ rg, const float* __restrict__ om,
    float* __restrict__ out) {
  const int b = blockIdx.x, tid = threadIdx.x;
  __shared__ float fh[256];
  __shared__ float sb[128];
  ((float2*)fh)[tid] = ((const float2*)(hfinal + b * 256))[tid];
  __syncthreads();
  const float4* wrow = (const float4*)(Wp + tid * 256);
  float acc = 0.f;
#pragma unroll 16
  for (int k4 = 0; k4 < 64; k4++) {
    float4 wv = wrow[k4];
    acc += wv.x * fh[4 * k4] + wv.y * fh[4 * k4 + 1] + wv.z * fh[4 * k4 + 2] +
           wv.w * fh[4 * k4 + 3];
  }
  sb[tid] = acc + bp[tid];
  __syncthreads();
  if (tid < 32) {
    const int dd = tid;
    float s0 = sb[dd * 4], s1 = sb[dd * 4 + 1], s2 = sb[dd * 4 + 2], s3 = sb[dd * 4 + 3];
    float al = sigm(rld[dd]) * 0.15f + 0.85f;
    float at = sigm(rtd[dd]) * 0.25f + 0.70f;
    float g  = sigm(rg[dd]) * 0.20f + 0.80f;
    float cw = cosf(om[dd]), sw = sinf(om[dd]);
    float r00 = g * cw, r01 = -g * sw, r10 = g * sw, r11 = g * cw;
    float c0 = Cm[dd * 4], c1 = Cm[dd * 4 + 1], c2 = Cm[dd * 4 + 2], c3 = Cm[dd * 4 + 3];
    float* op = out + (size_t)b * PRED_ * D_ + dd;
    for (int t = 0; t < PRED_; t++) {
      float n0 = s0 * al, n1 = s1 * at;
      float n2 = s2 * r00 + s3 * r10;
      float n3 = s2 * r01 + s3 * r11;
      op[(size_t)t * D_] = c0 * n0 + c1 * n1 + c2 * n2 + c3 * n3;
      s0 = n0; s1 = n1; s2 = n2; s3 = n3;
    }
  }
}

extern "C" void kernel_launch(void* const* d_in, const int* in_sizes, int n_in,
                              void* d_out, int out_size, void* d_ws,
                              size_t ws_size, hipStream_t stream) {
  (void)in_sizes; (void)n_in; (void)out_size;
  const float* x     = (const float*)d_in[0];
  const float* Wih0  = (const float*)d_in[1];
  const float* Whh0  = (const float*)d_in[2];
  const float* bih0  = (const float*)d_in[3];
  const float* bhh0  = (const float*)d_in[4];
  const float* Wih1  = (const float*)d_in[5];
  const float* Whh1  = (const float*)d_in[6];
  const float* bih1  = (const float*)d_in[7];
  const float* bhh1  = (const float*)d_in[8];
  const float* Wproj = (const float*)d_in[9];
  const float* bproj = (const float*)d_in[10];
  const float* Cm    = (const float*)d_in[11];
  const float* rld   = (const float*)d_in[12];
  const float* rtd   = (const float*)d_in[13];
  const float* rg    = (const float*)d_in[14];
  const float* om    = (const float*)d_in[15];
  float* out = (float*)d_out;

  char* ws = (char*)d_ws;
  const size_t wi0_off = 0;          // 768*32  f16 =     49,152 B
  const size_t wi1_off = 49152;      // 768*256 f16 =    393,216 B
  const size_t h16_off = 442368;     // 131072*256 f16 = 67,108,864 B
  const size_t hf_off  = 67551232;   // 256*256 f32 =    262,144 B
  const size_t need    = 67813376;
  if (ws_size < need) {
    fprintf(stderr, "kernel_launch: ws too small: have %zu need %zu — skipping\n",
            ws_size, need);
    return;
  }
  f16* wi016  = (f16*)(ws + wi0_off);
  f16* wi116  = (f16*)(ws + wi1_off);
  f16* h16    = (f16*)(ws + h16_off);
  float* hfin = (float*)(ws + hf_off);

  f32_to_f16_k<<<96, 256, 0, stream>>>(Wih0, wi016, G3_ * IN_);
  f32_to_f16_k<<<768, 256, 0, stream>>>(Wih1, wi116, G3_ * H_);
  gru_fused<0><<<B_, 512, 0, stream>>>((const void*)x,   wi016, bih0, Whh0, bhh0, h16, nullptr);
  gru_fused<1><<<B_, 512, 0, stream>>>((const void*)h16, wi116, bih1, Whh1, bhh1, nullptr, hfin);
  proj_rollout<<<B_, 128, 0, stream>>>(hfin, Wproj, bproj, Cm, rld, rtd, rg, om, out);
}

// Round 4
// 1599.391 us; speedup vs baseline: 1.1439x; 1.1439x over previous
//
#include <hip/hip_runtime.h>
#include <cstdio>
#include <cstdint>

typedef _Float16 f16;
typedef f16 hf2   __attribute__((ext_vector_type(2)));
typedef f16 f16x8 __attribute__((ext_vector_type(8)));
typedef float f32x4 __attribute__((ext_vector_type(4)));
typedef unsigned int   u32;
typedef unsigned short u16;

#define B_    256
#define S_    512
#define IN_   32
#define H_    256
#define G3_   768
#define D_    32
#define PRED_ 96
#define TC_   32          // time-chunk
#define XPAD_ 776         // padded xpc row (halves)

#if __has_builtin(__builtin_amdgcn_fdot2)
__device__ __forceinline__ float fdot2(hf2 a, hf2 b, float c) {
  return __builtin_amdgcn_fdot2(a, b, c, false);
}
#else
__device__ __forceinline__ float fdot2(hf2 a, hf2 b, float c) {
  return c + (float)a[0] * (float)b[0] + (float)a[1] * (float)b[1];
}
#endif

__device__ __forceinline__ float sigm(float x) {
  return __builtin_amdgcn_rcpf(1.f + __expf(-x));
}
__device__ __forceinline__ float tanh_fast(float x) {
  return 1.f - 2.f * __builtin_amdgcn_rcpf(__expf(2.f * x) + 1.f);
}
__device__ __forceinline__ hf2 bc2(u32 v) { return __builtin_bit_cast(hf2, v); }

__global__ void f32_to_f16_k(const float* __restrict__ in, f16* __restrict__ out, int n) {
  int i = blockIdx.x * blockDim.x + threadIdx.x;
  if (i < n) out[i] = (f16)in[i];
}

__device__ __forceinline__ f16x8 cvt8(const float* p) {
  float4 lo = ((const float4*)p)[0];
  float4 hi = ((const float4*)p)[1];
  f16x8 r;
  r[0] = (f16)lo.x; r[1] = (f16)lo.y; r[2] = (f16)lo.z; r[3] = (f16)lo.w;
  r[4] = (f16)hi.x; r[5] = (f16)hi.y; r[6] = (f16)hi.z; r[7] = (f16)hi.w;
  return r;
}

// One WG (512 thr) per batch row. Register-stationary fp16 W_hh:
// thread (p=tid>>1, kh=tid&1) owns rows {p, 256+p, 512+p} (r,z,n gates of
// hidden unit p), k-slice [kh*128, kh*128+128) -> 192 VGPRs of hf2.
// Per 32-step chunk an MFMA phase computes xpc = A_chunk @ Wih^T + bih into
// LDS; then 32 recurrence steps, single barrier each (double-buffered h).
template <int LAYER>
__global__ __launch_bounds__(512, 1) void gru_fused(
    const void* __restrict__ Asrc,   // L0: x f32 [B*S][32]; L1: h16 f16 [B*S][256]
    const f16* __restrict__ Wih,     // f16 [768][KK]
    const float* __restrict__ bih,   // [768]
    const float* __restrict__ Whh,   // f32 [768][256]
    const float* __restrict__ bhh,   // [768]
    f16* __restrict__ h16_out,       // [B*S][256] (LAYER==0)
    float* __restrict__ hfinal) {    // [B][256]   (LAYER==1)
  constexpr int KK = LAYER ? H_ : IN_;
  const int b   = blockIdx.x;
  const int tid = threadIdx.x;
  const int p  = tid >> 1, kh = tid & 1;
  const int wv = tid >> 6, lane = tid & 63, lm = lane & 15, q = lane >> 4;

  // ---- W_hh -> registers (fp16): w[g][64] hf2 ----
  hf2 w[3][64];
#pragma unroll
  for (int g = 0; g < 3; g++) {
    const float4* src = (const float4*)(Whh + (size_t)(g * 256 + p) * 256 + kh * 128);
#pragma unroll
    for (int u = 0; u < 32; u++) {
      float4 f = src[u];
      w[g][2 * u]     = hf2{(f16)f.x, (f16)f.y};
      w[g][2 * u + 1] = hf2{(f16)f.z, (f16)f.w};
    }
  }
  float bh[3];
#pragma unroll
  for (int g = 0; g < 3; g++) bh[g] = bhh[g * 256 + p];

  __shared__ u16 xpc[TC_ * XPAD_];                    // 49,664 B
  __shared__ __align__(16) u16 hbuf[2][256];          // double-buffered h (fp16)
  if (tid < 128) ((u32*)hbuf[0])[tid] = 0u;
  float h = 0.f;
  f16* h16p = (LAYER == 0) ? (h16_out + (size_t)b * S_ * H_) : nullptr;
  int cur = 0;

  for (int c = 0; c < S_ / TC_; ++c) {
    const int t0 = c * TC_;
    // ---------- xp GEMM phase: wave wv owns n in [wv*96, wv*96+96) ----------
#pragma unroll 1
    for (int nt = 0; nt < 6; ++nt) {
      const int n0 = wv * 96 + nt * 16;
      const f16* Bp = Wih + (size_t)(n0 + lm) * KK + q * 8;
      f32x4 ac0 = {0.f, 0.f, 0.f, 0.f}, ac1 = ac0;
#pragma unroll
      for (int k0 = 0; k0 < KK; k0 += 32) {
        f16x8 bv = *(const f16x8*)(Bp + k0);
        f16x8 a0, a1;
        if constexpr (LAYER == 0) {
          const float* xr = (const float*)Asrc + ((size_t)b * S_ + t0 + lm) * IN_ + k0 + q * 8;
          a0 = cvt8(xr);
          a1 = cvt8(xr + 16 * IN_);
        } else {
          const f16* ar = (const f16*)Asrc + ((size_t)b * S_ + t0 + lm) * H_ + k0 + q * 8;
          a0 = *(const f16x8*)ar;
          a1 = *(const f16x8*)(ar + 16 * H_);
        }
        ac0 = __builtin_amdgcn_mfma_f32_16x16x32_f16(a0, bv, ac0, 0, 0, 0);
        ac1 = __builtin_amdgcn_mfma_f32_16x16x32_f16(a1, bv, ac1, 0, 0, 0);
      }
      const float bb = bih[n0 + lm];
#pragma unroll
      for (int r = 0; r < 4; ++r) {   // D: col=lane&15 (n), row=q*4+r (m)
        xpc[(q * 4 + r) * XPAD_ + n0 + lm]      = __builtin_bit_cast(u16, (f16)(ac0[r] + bb));
        xpc[(16 + q * 4 + r) * XPAD_ + n0 + lm] = __builtin_bit_cast(u16, (f16)(ac1[r] + bb));
      }
    }
    __syncthreads();

    // ---------- 32 recurrence steps, one barrier each ----------
    for (int tl = 0; tl < TC_; ++tl) {
      float ar = 0.f, az = 0.f, an = 0.f, ar2 = 0.f, az2 = 0.f, an2 = 0.f;
      // kh's k-slice is [kh*128, kh*128+128): uint4 = 8 halves -> offset kh*16
      const uint4* hb = (const uint4*)hbuf[cur] + kh * 16;
#pragma unroll
      for (int cc = 0; cc < 16; ++cc) {
        uint4 hv = hb[cc];
        hf2 h0 = bc2(hv.x), h1 = bc2(hv.y), h2v = bc2(hv.z), h3 = bc2(hv.w);
        ar  = fdot2(w[0][4 * cc],     h0,  ar);
        ar2 = fdot2(w[0][4 * cc + 1], h1,  ar2);
        ar  = fdot2(w[0][4 * cc + 2], h2v, ar);
        ar2 = fdot2(w[0][4 * cc + 3], h3,  ar2);
        az  = fdot2(w[1][4 * cc],     h0,  az);
        az2 = fdot2(w[1][4 * cc + 1], h1,  az2);
        az  = fdot2(w[1][4 * cc + 2], h2v, az);
        az2 = fdot2(w[1][4 * cc + 3], h3,  az2);
        an  = fdot2(w[2][4 * cc],     h0,  an);
        an2 = fdot2(w[2][4 * cc + 1], h1,  an2);
        an  = fdot2(w[2][4 * cc + 2], h2v, an);
        an2 = fdot2(w[2][4 * cc + 3], h3,  an2);
      }
      ar += ar2; az += az2; an += an2;
      ar += __shfl_xor(ar, 1);
      az += __shfl_xor(az, 1);
      an += __shfl_xor(an, 1);

      const u16* xrow = xpc + tl * XPAD_;
      float xr = (float)__builtin_bit_cast(f16, xrow[p]);
      float xz = (float)__builtin_bit_cast(f16, xrow[256 + p]);
      float xn = (float)__builtin_bit_cast(f16, xrow[512 + p]);
      float r = sigm(xr + ar + bh[0]);
      float z = sigm(xz + az + bh[1]);
      float n = tanh_fast(xn + r * (an + bh[2]));
      h = (1.f - z) * n + z * h;

      if (kh == 0) {
        hbuf[cur ^ 1][p] = __builtin_bit_cast(u16, (f16)h);
        if constexpr (LAYER == 0) h16p[(size_t)(t0 + tl) * H_ + p] = (f16)h;
      }
      __syncthreads();   // step-t reads done AND step-t writes visible
      cur ^= 1;
    }
  }
  if constexpr (LAYER == 1) {
    if (kh == 0) hfinal[b * H_ + p] = h;
  }
}

// ---------------- projection + 96-step rollout ------------------------------
__global__ __launch_bounds__(128) void proj_rollout(
    const float* __restrict__ hfinal, const float* __restrict__ Wp,
    const float* __restrict__ bp, const float* __restrict__ Cm,
    const float* __restrict__ rld, const float* __restrict__ rtd,
    const float* __restrict__ rg, const float* __restrict__ om,
    float* __restrict__ out) {
  const int b = blockIdx.x, tid = threadIdx.x;
  __shared__ float fh[256];
  __shared__ float sb[128];
  ((float2*)fh)[tid] = ((const float2*)(hfinal + b * 256))[tid];
  __syncthreads();
  const float4* wrow = (const float4*)(Wp + tid * 256);
  float acc = 0.f;
#pragma unroll 16
  for (int k4 = 0; k4 < 64; k4++) {
    float4 wv = wrow[k4];
    acc += wv.x * fh[4 * k4] + wv.y * fh[4 * k4 + 1] + wv.z * fh[4 * k4 + 2] +
           wv.w * fh[4 * k4 + 3];
  }
  sb[tid] = acc + bp[tid];
  __syncthreads();
  if (tid < 32) {
    const int dd = tid;
    float s0 = sb[dd * 4], s1 = sb[dd * 4 + 1], s2 = sb[dd * 4 + 2], s3 = sb[dd * 4 + 3];
    float al = sigm(rld[dd]) * 0.15f + 0.85f;
    float at = sigm(rtd[dd]) * 0.25f + 0.70f;
    float g  = sigm(rg[dd]) * 0.20f + 0.80f;
    float cw = cosf(om[dd]), sw = sinf(om[dd]);
    float r00 = g * cw, r01 = -g * sw, r10 = g * sw, r11 = g * cw;
    float c0 = Cm[dd * 4], c1 = Cm[dd * 4 + 1], c2 = Cm[dd * 4 + 2], c3 = Cm[dd * 4 + 3];
    float* op = out + (size_t)b * PRED_ * D_ + dd;
    for (int t = 0; t < PRED_; t++) {
      float n0 = s0 * al, n1 = s1 * at;
      float n2 = s2 * r00 + s3 * r10;
      float n3 = s2 * r01 + s3 * r11;
      op[(size_t)t * D_] = c0 * n0 + c1 * n1 + c2 * n2 + c3 * n3;
      s0 = n0; s1 = n1; s2 = n2; s3 = n3;
    }
  }
}

extern "C" void kernel_launch(void* const* d_in, const int* in_sizes, int n_in,
                              void* d_out, int out_size, void* d_ws,
                              size_t ws_size, hipStream_t stream) {
  (void)in_sizes; (void)n_in; (void)out_size;
  const float* x     = (const float*)d_in[0];
  const float* Wih0  = (const float*)d_in[1];
  const float* Whh0  = (const float*)d_in[2];
  const float* bih0  = (const float*)d_in[3];
  const float* bhh0  = (const float*)d_in[4];
  const float* Wih1  = (const float*)d_in[5];
  const float* Whh1  = (const float*)d_in[6];
  const float* bih1  = (const float*)d_in[7];
  const float* bhh1  = (const float*)d_in[8];
  const float* Wproj = (const float*)d_in[9];
  const float* bproj = (const float*)d_in[10];
  const float* Cm    = (const float*)d_in[11];
  const float* rld   = (const float*)d_in[12];
  const float* rtd   = (const float*)d_in[13];
  const float* rg    = (const float*)d_in[14];
  const float* om    = (const float*)d_in[15];
  float* out = (float*)d_out;

  char* ws = (char*)d_ws;
  const size_t wi0_off = 0;          // 768*32  f16 =     49,152 B
  const size_t wi1_off = 49152;      // 768*256 f16 =    393,216 B
  const size_t h16_off = 442368;     // 131072*256 f16 = 67,108,864 B
  const size_t hf_off  = 67551232;   // 256*256 f32 =    262,144 B
  const size_t need    = 67813376;
  if (ws_size < need) {
    fprintf(stderr, "kernel_launch: ws too small: have %zu need %zu — skipping\n",
            ws_size, need);
    return;
  }
  f16* wi016  = (f16*)(ws + wi0_off);
  f16* wi116  = (f16*)(ws + wi1_off);
  f16* h16    = (f16*)(ws + h16_off);
  float* hfin = (float*)(ws + hf_off);

  f32_to_f16_k<<<96, 256, 0, stream>>>(Wih0, wi016, G3_ * IN_);
  f32_to_f16_k<<<768, 256, 0, stream>>>(Wih1, wi116, G3_ * H_);
  gru_fused<0><<<B_, 512, 0, stream>>>((const void*)x,   wi016, bih0, Whh0, bhh0, h16, nullptr);
  gru_fused<1><<<B_, 512, 0, stream>>>((const void*)h16, wi116, bih1, Whh1, bhh1, nullptr, hfin);
  proj_rollout<<<B_, 128, 0, stream>>>(hfin, Wproj, bproj, Cm, rld, rtd, rg, om, out);
}